// Round 8
// baseline (44.207 us; speedup 1.0000x reference)
//
#include <hip/hip_runtime.h>

#define B_ 2
#define L_ 256
#define H_ 256
#define A_ 32
#define P_ 64
#define PSTR 76    // posT LDS row stride (floats)
#define TSTR 516   // out-tile LDS row stride (floats): 8*64 + 4

typedef __bf16 bf16x8 __attribute__((ext_vector_type(8)));
typedef float  f32x4  __attribute__((ext_vector_type(4)));

// Single kernel, 256 blocks x 256 threads (<=3 blocks/CU capacity -> all co-resident).
// Stage A: block bid computes h and g (bf16, g transposed [r][p][a]) for rows 2bid..2bid+1.
// Barrier: syncthreads -> threadfence (L2 wb) -> atomicAdd; poll via atomicAdd(cnt,0)
// (RMW at coherency point, NO per-poll cache invalidation - R5's mistake), then one
// threadfence (inv) after the poll.
// Stage B: block owns j-range jt*8..+7 and 4 i-tiles of 16 rows: gfrag loaded once;
// mfma(A=g,B=h) -> D[m=p][n=i]; fused pos epilogue staged in LDS; linear PLAIN stores.
__global__ __launch_bounds__(256) void fused(
    const float* __restrict__ x,     // [B,L,H]
    const float* __restrict__ in_w,  // [A,H]
    const float* __restrict__ in_b,  // [A]
    const float* __restrict__ out_w, // [P, A*A]
    const float* __restrict__ out_b, // [P]
    const float* __restrict__ pos_w, // [P,17]
    const float* __restrict__ pos_b, // [P]
    __bf16* __restrict__ gb,         // [B*L][P][A] (ws)
    __bf16* __restrict__ hb,         // [B*L][A]   (ws)
    unsigned int* cnt,               // (ws) zeroed per call by memset node
    float* __restrict__ out)         // [B,L,L,P]
{
    __shared__ float xs[2 * H_];
    __shared__ float hl[2][A_];
    __shared__ float posT[17 * PSTR];
    __shared__ float tile[16][TSTR];

    const int t = threadIdx.x;
    const int bid = blockIdx.x;

    // ---------------- stage A ----------------
    const int r0 = bid * 2;
    if (t < 128) ((float4*)xs)[t] = ((const float4*)(x + (size_t)r0 * H_))[t];
    __syncthreads();

    {   // h: 2 rows x 32 outputs, 4 threads per 256-dot
        const int jj = t >> 7;
        const int rem = t & 127;
        const int a = rem >> 2;
        const int q = rem & 3;
        const float4* w4 = (const float4*)(in_w + a * H_ + q * 64);
        const float4* xv4 = (const float4*)(xs + jj * H_ + q * 64);
        float s = 0.f;
        #pragma unroll
        for (int m = 0; m < 16; ++m) {
            float4 w = w4[m], xv = xv4[m];
            s += w.x * xv.x + w.y * xv.y + w.z * xv.z + w.w * xv.w;
        }
        s += __shfl_xor(s, 1);
        s += __shfl_xor(s, 2);
        if (q == 0) {
            float hv = s + in_b[a];
            hl[jj][a] = hv;
            hb[(r0 + jj) * A_ + a] = (__bf16)hv;
        }
    }
    __syncthreads();

    {   // g: thread owns p = t&63, a-range (t>>6)*8..+7
        const int p = t & 63;
        const int ag = t >> 6;
        float sacc[2][8];
        #pragma unroll
        for (int k = 0; k < 8; ++k) {
            const int a = ag * 8 + k;
            const float4* wrow = (const float4*)(out_w + (size_t)p * (A_ * A_) + a * A_);
            float4 w[8];
            #pragma unroll
            for (int m = 0; m < 8; ++m) w[m] = wrow[m];
            #pragma unroll
            for (int jj = 0; jj < 2; ++jj) {
                const float4* hh = (const float4*)hl[jj];   // uniform -> broadcast
                float s = 0.f;
                #pragma unroll
                for (int m = 0; m < 8; ++m) {
                    float4 h4 = hh[m];
                    s += w[m].x * h4.x + w[m].y * h4.y + w[m].z * h4.z + w[m].w * h4.w;
                }
                sacc[jj][k] = s;
            }
        }
        #pragma unroll
        for (int jj = 0; jj < 2; ++jj) {
            bf16x8 v;
            #pragma unroll
            for (int e = 0; e < 8; ++e) v[e] = (__bf16)sacc[jj][e];
            *(bf16x8*)(gb + ((size_t)((r0 + jj) * P_ + p)) * A_ + ag * 8) = v;
        }
    }

    // ---------------- posT build (before barrier: overlaps other blocks' stage A) --------
    for (int e = t; e < 17 * P_; e += 256) {
        const int d = e >> 6, p = e & 63;
        posT[d * PSTR + p] = pos_w[p * 17 + d] + pos_b[p] + out_b[p];
    }

    // ---------------- grid barrier ----------------
    __syncthreads();                  // all stage-A stores issued (vmcnt drained)
    if (t == 0) {
        __threadfence();              // L2 writeback: gb/hb visible device-wide
        atomicAdd(cnt, 1u);           // device-scope, coherency-point RMW
        while (atomicAdd(cnt, 0u) < 256u)   // RMW poll: no cache-inv per iteration
            __builtin_amdgcn_s_sleep(16);
        __threadfence();              // one-time invalidate: see other XCDs' gb/hb
    }
    __syncthreads();

    // ---------------- stage B ----------------
    const int jt = bid & 31;         // j-tile 0..31
    const int ib = bid >> 5;         // 0..7
    const int b = ib >> 2;           // 0..1
    const int it4 = ib & 3;          // i-quarter 0..3
    const int j0 = jt * 8;

    const int lane = t & 63;
    const int w = t >> 6;            // wave 0..3
    const int l15 = lane & 15;
    const int hi = lane >> 4;        // 0..3
    const int p_r0 = hi * 4;

    // gfrag: loaded ONCE, reused for 4 i-tiles
    bf16x8 gfrag[2][4];
    #pragma unroll
    for (int tj = 0; tj < 2; ++tj) {
        const int j = j0 + w * 2 + tj;
        const __bf16* gr = gb + ((size_t)(b * L_ + j)) * (P_ * A_);
        #pragma unroll
        for (int pg = 0; pg < 4; ++pg)
            gfrag[tj][pg] = *(const bf16x8*)(gr + (pg * 16 + l15) * A_ + hi * 8);
    }

    const f32x4 zero = {0.f, 0.f, 0.f, 0.f};

    #pragma unroll
    for (int tt = 0; tt < 4; ++tt) {
        const int i0 = it4 * 64 + tt * 16;
        const int i = i0 + l15;

        const bf16x8 hfrag = *(const bf16x8*)(hb + ((size_t)(b * L_ + i)) * A_ + hi * 8);

        #pragma unroll
        for (int tj = 0; tj < 2; ++tj) {
            const int jl = w * 2 + tj;
            const int j = j0 + jl;

            f32x4 acc[4];
            #pragma unroll
            for (int pg = 0; pg < 4; ++pg)
                acc[pg] = __builtin_amdgcn_mfma_f32_16x16x32_bf16(gfrag[tj][pg], hfrag, zero, 0, 0, 0);

            int d = i - j;
            d = d < -8 ? -8 : (d > 8 ? 8 : d);
            d += 8;

            #pragma unroll
            for (int pg = 0; pg < 4; ++pg) {
                const f32x4 pe = *(const f32x4*)(posT + d * PSTR + pg * 16 + p_r0);
                *(f32x4*)&tile[l15][jl * 64 + pg * 16 + p_r0] = acc[pg] + pe;
            }
        }
        __syncthreads();

        // linear read-out: row ir = 512 consecutive floats of out; PLAIN stores
        const int ir = t >> 4;
        const int c  = t & 15;
        float* orow = out + (((size_t)(b * L_ + i0 + ir)) * L_ + j0) * P_;
        #pragma unroll
        for (int m = 0; m < 8; ++m) {
            const int f4 = m * 16 + c;
            *(f32x4*)(orow + f4 * 4) = *(const f32x4*)&tile[ir][f4 * 4];
        }
        __syncthreads();
    }
}

extern "C" void kernel_launch(void* const* d_in, const int* in_sizes, int n_in,
                              void* d_out, int out_size, void* d_ws, size_t ws_size,
                              hipStream_t stream) {
    const float* x     = (const float*)d_in[0];
    const float* in_w  = (const float*)d_in[1];
    const float* in_b  = (const float*)d_in[2];
    const float* out_w = (const float*)d_in[3];
    const float* out_b = (const float*)d_in[4];
    const float* pos_w = (const float*)d_in[5];
    const float* pos_b = (const float*)d_in[6];
    float* out = (float*)d_out;

    __bf16* gb = (__bf16*)d_ws;                                   // 2 MB
    __bf16* hb = gb + (size_t)B_ * L_ * P_ * A_;                  // +32 KB
    unsigned int* cnt = (unsigned int*)((char*)d_ws +
        (size_t)B_ * L_ * P_ * A_ * 2 + (size_t)B_ * L_ * A_ * 2);

    hipMemsetAsync(cnt, 0, 4, stream);
    fused<<<dim3(256), 256, 0, stream>>>(x, in_w, in_b, out_w, out_b,
                                         pos_w, pos_b, gb, hb, cnt, out);
}

// Round 9
// 21.490 us; speedup vs baseline: 2.0571x; 2.0571x over previous
//
#include <hip/hip_runtime.h>

#define B_ 2
#define L_ 256
#define H_ 256
#define A_ 32
#define P_ 64
#define PSTR 76    // posT LDS row stride (floats)
#define TSTR 516   // out-tile LDS row stride (floats): 8*64 + 4
#define XSTR 260   // x/in_w LDS row stride (floats): 16B-aligned, bank-spread

typedef __bf16 bf16x8 __attribute__((ext_vector_type(8)));
typedef float  f32x4  __attribute__((ext_vector_type(4)));

// k1: 512 blocks = 64 row-groups (8 rows) x 8 p-eighths (8 p each).
// Each block: stage x(8 rows) + in_w into LDS; h[8][32] via 1-thread-per-dot
// (redundant x8 across p-slices, trivial); g[j][a][p-slice] = sum_c out_w[p,a*32+c]*h[j,c].
// out_w traffic: 32 KB/block -> 16 MB total (was 256 KB/block -> 67 MB).
__global__ __launch_bounds__(256) void k1_proj(
    const float* __restrict__ x,     // [B,L,H]
    const float* __restrict__ in_w,  // [A,H]
    const float* __restrict__ in_b,  // [A]
    const float* __restrict__ out_w, // [P, A*A]
    __bf16* __restrict__ gb,         // [B*L][P][A] bf16
    __bf16* __restrict__ hb)         // [B*L][A]   bf16
{
    __shared__ float xs[8][XSTR];
    __shared__ float ws[32][XSTR];
    __shared__ float hl[8][A_];

    const int t = threadIdx.x;
    const int rowg = blockIdx.x >> 3;     // 0..63
    const int pe   = blockIdx.x & 7;      // p-eighth
    const int r0 = rowg * 8;              // flat row base (b*L+l)

    // stage x: 8 rows x 256 f32 = 512 float4
    #pragma unroll
    for (int u = t; u < 512; u += 256) {
        const int row = u >> 6, c4 = u & 63;
        *(float4*)&xs[row][c4 * 4] = ((const float4*)(x + (size_t)(r0 + row) * H_))[c4];
    }
    // stage in_w: 32 x 256 f32 = 2048 float4
    #pragma unroll
    for (int u = t; u < 2048; u += 256) {
        const int a = u >> 6, c4 = u & 63;
        *(float4*)&ws[a][c4 * 4] = ((const float4*)(in_w + (size_t)a * H_))[c4];
    }
    __syncthreads();

    // h: thread t -> row t>>5, a t&31; full 256-dot from LDS
    {
        const int row = t >> 5, a = t & 31;
        float s = 0.f;
        #pragma unroll
        for (int c4 = 0; c4 < 64; ++c4) {
            const float4 xv = *(const float4*)&xs[row][c4 * 4];
            const float4 wv = *(const float4*)&ws[a][c4 * 4];
            s += xv.x * wv.x + xv.y * wv.y + xv.z * wv.z + xv.w * wv.w;
        }
        const float hv = s + in_b[a];
        hl[row][a] = hv;
        if (pe == 0) hb[(size_t)(r0 + row) * A_ + a] = (__bf16)hv;
    }
    __syncthreads();

    // g: thread t -> p = pe*8 + (t>>5), a = t&31; 8 j-rows
    {
        const int p = pe * 8 + (t >> 5);
        const int a = t & 31;
        const float4* wrow = (const float4*)(out_w + (size_t)p * (A_ * A_) + a * A_);
        float4 w[8];
        #pragma unroll
        for (int m = 0; m < 8; ++m) w[m] = wrow[m];
        float sac[8];
        #pragma unroll
        for (int jj = 0; jj < 8; ++jj) {
            const float4* hh = (const float4*)hl[jj];   // uniform -> broadcast
            float s = 0.f;
            #pragma unroll
            for (int m = 0; m < 8; ++m) {
                const float4 h4 = hh[m];
                s += w[m].x * h4.x + w[m].y * h4.y + w[m].z * h4.z + w[m].w * h4.w;
            }
            sac[jj] = s;
        }
        #pragma unroll
        for (int jj = 0; jj < 8; ++jj)
            gb[((size_t)(r0 + jj) * P_ + p) * A_ + a] = (__bf16)sac[jj];
    }
}

// k2: out[b,i,j,p] = sum_a g[j,a,p] h[i,a] via mfma(A=g, B=h): D[m=p][n=i].
// Tile 16i x 8j x 64p per block. Epilogue: fuse acc+posT into LDS tile,
// then linear cooperative NT stores (256B-contiguous per 16-lane group).
// (byte-identical to R6's measured-best k2)
__global__ __launch_bounds__(256) void k2_mfma(
    const __bf16* __restrict__ gb,   // [B*L][P][A]
    const __bf16* __restrict__ hb,   // [B*L][A]
    const float* __restrict__ out_b, // [P]
    const float* __restrict__ pos_w, // [P,17]
    const float* __restrict__ pos_b, // [P]
    float* __restrict__ out)         // [B,L,L,P]
{
    __shared__ float posT[17 * PSTR];
    __shared__ float tile[16][TSTR];
    const int t = threadIdx.x;

    for (int e = t; e < 17 * P_; e += 256) {
        const int d = e >> 6, p = e & 63;
        posT[d * PSTR + p] = pos_w[p * 17 + d] + pos_b[p] + out_b[p];
    }
    __syncthreads();

    const int lane = t & 63;
    const int w = t >> 6;            // wave 0..3
    const int j0 = blockIdx.x * 8;
    const int i0 = blockIdx.y * 16;
    const int b = blockIdx.z;

    const int l15 = lane & 15;
    const int hi = lane >> 4;        // 0..3
    const int i = i0 + l15;
    const int p_r0 = hi * 4;         // p offset within 16-p group

    const bf16x8 hfrag = *(const bf16x8*)(hb + ((size_t)(b * L_ + i)) * A_ + hi * 8);
    const f32x4 zero = {0.f, 0.f, 0.f, 0.f};

    #pragma unroll
    for (int tj = 0; tj < 2; ++tj) {
        const int jl = w * 2 + tj;   // local j 0..7
        const int j = j0 + jl;
        const __bf16* gr = gb + ((size_t)(b * L_ + j)) * (P_ * A_);

        bf16x8 gfrag[4];
        #pragma unroll
        for (int pg = 0; pg < 4; ++pg)
            gfrag[pg] = *(const bf16x8*)(gr + (pg * 16 + l15) * A_ + hi * 8);

        f32x4 acc[4];
        #pragma unroll
        for (int pg = 0; pg < 4; ++pg)
            acc[pg] = __builtin_amdgcn_mfma_f32_16x16x32_bf16(gfrag[pg], hfrag, zero, 0, 0, 0);

        int d = i - j;
        d = d < -8 ? -8 : (d > 8 ? 8 : d);
        d += 8;

        #pragma unroll
        for (int pg = 0; pg < 4; ++pg) {
            const f32x4 pe = *(const f32x4*)(posT + d * PSTR + pg * 16 + p_r0);
            *(f32x4*)&tile[l15][jl * 64 + pg * 16 + p_r0] = acc[pg] + pe;
        }
    }
    __syncthreads();

    const int ir = t >> 4;           // 0..15
    const int c  = t & 15;           // 0..15
    float* orow = out + (((size_t)(b * L_ + i0 + ir)) * L_ + j0) * P_;
    #pragma unroll
    for (int m = 0; m < 8; ++m) {
        const int f4 = m * 16 + c;
        const f32x4 v = *(const f32x4*)&tile[ir][f4 * 4];
        __builtin_nontemporal_store(v, (f32x4*)(orow + f4 * 4));
    }
}

extern "C" void kernel_launch(void* const* d_in, const int* in_sizes, int n_in,
                              void* d_out, int out_size, void* d_ws, size_t ws_size,
                              hipStream_t stream) {
    const float* x     = (const float*)d_in[0];
    const float* in_w  = (const float*)d_in[1];
    const float* in_b  = (const float*)d_in[2];
    const float* out_w = (const float*)d_in[3];
    const float* out_b = (const float*)d_in[4];
    const float* pos_w = (const float*)d_in[5];
    const float* pos_b = (const float*)d_in[6];
    float* out = (float*)d_out;

    __bf16* gb = (__bf16*)d_ws;                                   // 2 MB
    __bf16* hb = gb + (size_t)B_ * L_ * P_ * A_;                  // +32 KB

    k1_proj<<<dim3(512), 256, 0, stream>>>(x, in_w, in_b, out_w, gb, hb);
    k2_mfma<<<dim3(L_ / 8, L_ / 16, B_), 256, 0, stream>>>(gb, hb, out_b, pos_w, pos_b, out);
}